// Round 1
// baseline (174.904 us; speedup 1.0000x reference)
//
#include <hip/hip_runtime.h>

#define BATCH 16
#define NANCH 25200
#define NCOLS 85
#define CONF_COL 4
#define CONF_THRES 0.25f
#define MAX_DET 300
#define BLOCK 1024
#define NWAVES (BLOCK / 64)

// One block per image. Phase 1: block-wide stable stream compaction of the
// first MAX_DET passing row indices into LDS (early exit once found).
// Phase 2: cooperative copy of those rows to out; invalid slots zeroed.
__global__ __launch_bounds__(BLOCK) void nms_prefilter_kernel(
    const float* __restrict__ pred, float* __restrict__ out) {
    __shared__ int sel_idx[MAX_DET];
    __shared__ int wave_sums[NWAVES];

    const int b = blockIdx.x;
    const int tid = threadIdx.x;
    const int lane = tid & 63;
    const int wave = tid >> 6;
    const float* img = pred + (size_t)b * NANCH * NCOLS;

    int base = 0;  // passing rows found so far (uniform across block)

    for (int chunk = 0; chunk < NANCH; chunk += BLOCK) {
        const int i = chunk + tid;
        int flag = 0;
        if (i < NANCH) {
            flag = (img[(size_t)i * NCOLS + CONF_COL] > CONF_THRES) ? 1 : 0;
        }
        // in-wave exclusive prefix via ballot
        unsigned long long ball = __ballot(flag);
        int excl_in_wave = __popcll(ball & ((1ull << lane) - 1ull));
        if (lane == 0) wave_sums[wave] = __popcll(ball);
        __syncthreads();
        int wave_offset = 0;
        for (int w = 0; w < wave; ++w) wave_offset += wave_sums[w];
        int chunk_total = wave_offset;
        for (int w = wave; w < NWAVES; ++w) chunk_total += wave_sums[w];

        int rank = base + wave_offset + excl_in_wave;
        if (flag && rank < MAX_DET) sel_idx[rank] = i;

        base += chunk_total;              // uniform across block
        __syncthreads();                  // protect wave_sums reuse + sel_idx
        if (base >= MAX_DET) break;       // uniform branch
    }

    const int count = base < MAX_DET ? base : MAX_DET;
    float* dst = out + (size_t)b * MAX_DET * NCOLS;

    // Phase 2: write all MAX_DET*NCOLS outputs for this image.
    for (int t = tid; t < MAX_DET * NCOLS; t += BLOCK) {
        const int j = t / NCOLS;
        const int c = t - j * NCOLS;
        float v = 0.0f;
        if (j < count) {
            v = img[(size_t)sel_idx[j] * NCOLS + c];
        }
        dst[t] = v;
    }
}

extern "C" void kernel_launch(void* const* d_in, const int* in_sizes, int n_in,
                              void* d_out, int out_size, void* d_ws, size_t ws_size,
                              hipStream_t stream) {
    const float* pred = (const float*)d_in[0];
    float* out = (float*)d_out;
    nms_prefilter_kernel<<<BATCH, BLOCK, 0, stream>>>(pred, out);
}

// Round 2
// 165.889 us; speedup vs baseline: 1.0543x; 1.0543x over previous
//
#include <hip/hip_runtime.h>

#define BATCH 16
#define NANCH 25200
#define NCOLS 85
#define CONF_COL 4
#define CONF_THRES 0.25f
#define MAX_DET 300
#define BLOCK 1024
#define NWAVES (BLOCK / 64)
#define WS_STRIDE (MAX_DET + 1)          // per-image ints in ws: [count, idx0..idx299]
#define TOTAL_OUT (BATCH * MAX_DET * NCOLS)

// Kernel A: one block per image. Block-wide stable stream compaction of the
// first MAX_DET passing row indices into LDS (early exit once found), then
// dump count + indices to workspace.
__global__ __launch_bounds__(BLOCK) void scan_kernel(
    const float* __restrict__ pred, int* __restrict__ ws) {
    __shared__ int sel_idx[MAX_DET];
    __shared__ int wave_sums[NWAVES];

    const int b = blockIdx.x;
    const int tid = threadIdx.x;
    const int lane = tid & 63;
    const int wave = tid >> 6;
    const float* img = pred + (size_t)b * NANCH * NCOLS;

    int base = 0;  // passing rows found so far (uniform across block)

    for (int chunk = 0; chunk < NANCH; chunk += BLOCK) {
        const int i = chunk + tid;
        int flag = 0;
        if (i < NANCH) {
            flag = (img[(size_t)i * NCOLS + CONF_COL] > CONF_THRES) ? 1 : 0;
        }
        unsigned long long ball = __ballot(flag);
        int excl_in_wave = __popcll(ball & ((1ull << lane) - 1ull));
        if (lane == 0) wave_sums[wave] = __popcll(ball);
        __syncthreads();
        int wave_offset = 0;
        for (int w = 0; w < wave; ++w) wave_offset += wave_sums[w];
        int chunk_total = wave_offset;
        for (int w = wave; w < NWAVES; ++w) chunk_total += wave_sums[w];

        int rank = base + wave_offset + excl_in_wave;
        if (flag && rank < MAX_DET) sel_idx[rank] = i;

        base += chunk_total;              // uniform across block
        __syncthreads();                  // protect wave_sums reuse + sel_idx
        if (base >= MAX_DET) break;       // uniform branch
    }

    const int count = base < MAX_DET ? base : MAX_DET;
    int* wsb = ws + b * WS_STRIDE;
    if (tid == 0) wsb[0] = count;
    // pad unreached sel slots with 0 so kernel B's gather address is benign
    for (int j = tid; j < MAX_DET; j += BLOCK) {
        wsb[1 + j] = (j < count) ? sel_idx[j] : 0;
    }
}

// Kernel B: fully element-parallel gather/zero of the [B, 300, 85] output.
__global__ __launch_bounds__(256) void copy_kernel(
    const float* __restrict__ pred, const int* __restrict__ ws,
    float* __restrict__ out) {
    const int t = blockIdx.x * 256 + threadIdx.x;
    if (t >= TOTAL_OUT) return;
    const int b = t / (MAX_DET * NCOLS);
    const int r = t - b * (MAX_DET * NCOLS);
    const int j = r / NCOLS;
    const int c = r - j * NCOLS;
    const int* wsb = ws + b * WS_STRIDE;
    const int count = wsb[0];
    float v = 0.0f;
    if (j < count) {
        const int row = wsb[1 + j];
        v = pred[((size_t)b * NANCH + row) * NCOLS + c];
    }
    out[t] = v;
}

extern "C" void kernel_launch(void* const* d_in, const int* in_sizes, int n_in,
                              void* d_out, int out_size, void* d_ws, size_t ws_size,
                              hipStream_t stream) {
    const float* pred = (const float*)d_in[0];
    float* out = (float*)d_out;
    int* ws = (int*)d_ws;
    scan_kernel<<<BATCH, BLOCK, 0, stream>>>(pred, ws);
    copy_kernel<<<(TOTAL_OUT + 255) / 256, 256, 0, stream>>>(pred, ws, out);
}